// Round 3
// baseline (211.685 us; speedup 1.0000x reference)
//
#include <hip/hip_runtime.h>
#include <math.h>

#define B_SZ 32
#define L_SZ 32768
#define T_SZ 1024
#define PS_SZ 32
#define D_SZ 256
#define SM_M 10.0f   // static softmax max-shift; scores ~N(0,1), max << 10

typedef float f32x4 __attribute__((ext_vector_type(4)));
typedef float f32x16 __attribute__((ext_vector_type(16)));
typedef short s16x8 __attribute__((ext_vector_type(8)));
typedef unsigned short u16x8 __attribute__((ext_vector_type(8)));
typedef unsigned int u32;
typedef unsigned int u32x4 __attribute__((ext_vector_type(4)));

__device__ __forceinline__ unsigned short f2bf(float f) {
  union { float f; unsigned int u; } v; v.f = f;
  unsigned int r = v.u + 0x7FFFu + ((v.u >> 16) & 1u);
  return (unsigned short)(r >> 16);
}

// ---------------- prep: stats partials + weight folds + counter zero ----------------
__global__ __launch_bounds__(256) void prep_kernel(const float* __restrict__ x,
                                                   float* __restrict__ sgpart,
                                                   const float* __restrict__ Wp,
                                                   const float* __restrict__ bp,
                                                   const float* __restrict__ Wq,
                                                   const float* __restrict__ bq,
                                                   const float* __restrict__ Wo,
                                                   const float* __restrict__ bo,
                                                   const float* __restrict__ Wh,
                                                   const float* __restrict__ bh,
                                                   float* __restrict__ Wcb,
                                                   unsigned short* __restrict__ WqT,
                                                   unsigned short* __restrict__ WfT,
                                                   float* __restrict__ bfp,
                                                   unsigned int* __restrict__ total,
                                                   float* __restrict__ lsum) {
  __shared__ float red[8];
  const int g = blockIdx.x, tid = threadIdx.x;
  const int w = tid >> 6, lane = tid & 63;
  if (g < 256) {
    const int b = g >> 3;
    const float* p = x + (size_t)b * L_SZ + (size_t)(g & 7) * 4096;
    float s = 0.f, ss = 0.f;
#pragma unroll
    for (int i = 0; i < 4; ++i) {
      float4 f = ((const float4*)p)[tid + i * 256];
      s += f.x + f.y + f.z + f.w;
      ss += f.x * f.x + f.y * f.y + f.z * f.z + f.w * f.w;
    }
#pragma unroll
    for (int off = 32; off >= 1; off >>= 1) {
      s += __shfl_down(s, off);
      ss += __shfl_down(ss, off);
    }
    if (lane == 0) { red[w] = s; red[4 + w] = ss; }
    __syncthreads();
    if (tid == 0) {
      sgpart[g * 2]     = red[0] + red[1] + red[2] + red[3];
      sgpart[g * 2 + 1] = red[4] + red[5] + red[6] + red[7];
    }
  } else if (g < 388) {
    int idx = (g - 256) * 256 + tid;
    if (idx < 33 * 768) {
      int p = idx / 768, j = idx % 768;
      const float* arow = (p < 32) ? (Wp + p * 256) : bp;
      float acc = (p < 32) ? 0.f : bq[j];
      for (int d = 0; d < 256; ++d) acc += arow[d] * Wq[d * 768 + j];
      if (p < 32) WqT[j * 32 + p] = f2bf(acc);
      else Wcb[j] = acc;
    } else {
      int k = idx - 33 * 768;
      if (k < 8192) {
        int p = k >> 8, d = k & 255;
        float acc = 0.f;
        for (int e = 0; e < 256; ++e) acc += Wo[d * 256 + e] * Wh[e * 32 + p];
        WfT[p * 256 + d] = f2bf(acc);
      } else if (k < 8224) {
        int p = k - 8192;
        float acc = bh[p];
        for (int e = 0; e < 256; ++e) acc += bo[e] * Wh[e * 32 + p];
        bfp[p] = acc;
      }
    }
  } else {
    if (tid == 0) { total[0] = 0u; lsum[0] = 0.f; }
  }
}

// ---------------- qkv MFMA GEMM (verified R7/R9); V kt-tiled transposed ----------------
__global__ __launch_bounds__(256) void qkv_kernel(const float* __restrict__ x,
                                                  const float* __restrict__ sgpart,
                                                  const unsigned short* __restrict__ WqT,
                                                  const float* __restrict__ Wcb,
                                                  unsigned short* __restrict__ Qb,
                                                  unsigned short* __restrict__ Kb,
                                                  unsigned short* __restrict__ Vtt) {
  __shared__ unsigned short T4[4][8448];
  const int tid = threadIdx.x;
  const int w = tid >> 6, lane = tid & 63;
  const int lo = lane & 15, quad = lane >> 4;
  unsigned short* Tw = T4[w];
  const int mbase = blockIdx.x * 128 + w * 32;
  const int b = mbase >> 10;
  float S = 0.f, SS = 0.f;
#pragma unroll
  for (int i = 0; i < 8; ++i) {
    S += sgpart[(b * 8 + i) * 2];
    SS += sgpart[(b * 8 + i) * 2 + 1];
  }
  const float mean = S * (1.f / (float)L_SZ);
  const float var = (SS - S * mean) * (1.f / (float)(L_SZ - 1));
  const float inv = 1.f / (sqrtf(var) + 1e-5f);
  s16x8 af0, af1;
  {
    float4 a = *(const float4*)&x[(size_t)(mbase + lo) * 32 + quad * 8];
    float4 c = *(const float4*)&x[(size_t)(mbase + lo) * 32 + quad * 8 + 4];
    af0[0] = (short)f2bf((a.x - mean) * inv); af0[1] = (short)f2bf((a.y - mean) * inv);
    af0[2] = (short)f2bf((a.z - mean) * inv); af0[3] = (short)f2bf((a.w - mean) * inv);
    af0[4] = (short)f2bf((c.x - mean) * inv); af0[5] = (short)f2bf((c.y - mean) * inv);
    af0[6] = (short)f2bf((c.z - mean) * inv); af0[7] = (short)f2bf((c.w - mean) * inv);
    float4 d = *(const float4*)&x[(size_t)(mbase + 16 + lo) * 32 + quad * 8];
    float4 e = *(const float4*)&x[(size_t)(mbase + 16 + lo) * 32 + quad * 8 + 4];
    af1[0] = (short)f2bf((d.x - mean) * inv); af1[1] = (short)f2bf((d.y - mean) * inv);
    af1[2] = (short)f2bf((d.z - mean) * inv); af1[3] = (short)f2bf((d.w - mean) * inv);
    af1[4] = (short)f2bf((e.x - mean) * inv); af1[5] = (short)f2bf((e.y - mean) * inv);
    af1[6] = (short)f2bf((e.z - mean) * inv); af1[7] = (short)f2bf((e.w - mean) * inv);
  }
  // Q (pre-scaled 1/16)
#pragma unroll 4
  for (int nt = 0; nt < 16; ++nt) {
    s16x8 bf = *(const s16x8*)&WqT[(size_t)(nt * 16 + lo) * 32 + quad * 8];
    f32x4 c0 = {0.f, 0.f, 0.f, 0.f}, c1 = {0.f, 0.f, 0.f, 0.f};
    c0 = __builtin_amdgcn_mfma_f32_16x16x32_bf16(af0, bf, c0, 0, 0, 0);
    c1 = __builtin_amdgcn_mfma_f32_16x16x32_bf16(af1, bf, c1, 0, 0, 0);
    const int col = nt * 16 + lo;
    const float bi = Wcb[col];
#pragma unroll
    for (int i = 0; i < 4; ++i) {
      Tw[(quad * 4 + i) * 264 + col]      = f2bf((c0[i] + bi) * 0.0625f);
      Tw[(16 + quad * 4 + i) * 264 + col] = f2bf((c1[i] + bi) * 0.0625f);
    }
  }
#pragma unroll
  for (int it = 0; it < 16; ++it) {
    const int gsub = it * 64 + lane;
    const int row = gsub >> 5, c16 = gsub & 31;
    *(u16x8*)&Qb[(size_t)(mbase + row) * 256 + c16 * 8] =
        *(const u16x8*)&Tw[row * 264 + c16 * 8];
  }
  // K
#pragma unroll 4
  for (int nt = 0; nt < 16; ++nt) {
    s16x8 bf = *(const s16x8*)&WqT[(size_t)(256 + nt * 16 + lo) * 32 + quad * 8];
    f32x4 c0 = {0.f, 0.f, 0.f, 0.f}, c1 = {0.f, 0.f, 0.f, 0.f};
    c0 = __builtin_amdgcn_mfma_f32_16x16x32_bf16(af0, bf, c0, 0, 0, 0);
    c1 = __builtin_amdgcn_mfma_f32_16x16x32_bf16(af1, bf, c1, 0, 0, 0);
    const int col = nt * 16 + lo;
    const float bi = Wcb[256 + col];
#pragma unroll
    for (int i = 0; i < 4; ++i) {
      Tw[(quad * 4 + i) * 264 + col]      = f2bf(c0[i] + bi);
      Tw[(16 + quad * 4 + i) * 264 + col] = f2bf(c1[i] + bi);
    }
  }
#pragma unroll
  for (int it = 0; it < 16; ++it) {
    const int gsub = it * 64 + lane;
    const int row = gsub >> 5, c16 = gsub & 31;
    *(u16x8*)&Kb[(size_t)(mbase + row) * 256 + c16 * 8] =
        *(const u16x8*)&Tw[row * 264 + c16 * 8];
  }
  // V transposed, kt-tiled: Vtt[(b*32+ktq)*8192 + d*32 + t_local]
#pragma unroll 4
  for (int nt2 = 0; nt2 < 16; ++nt2) {
    s16x8 aw = *(const s16x8*)&WqT[(size_t)(512 + nt2 * 16 + lo) * 32 + quad * 8];
    f32x4 c0 = {0.f, 0.f, 0.f, 0.f}, c1 = {0.f, 0.f, 0.f, 0.f};
    c0 = __builtin_amdgcn_mfma_f32_16x16x32_bf16(aw, af0, c0, 0, 0, 0);
    c1 = __builtin_amdgcn_mfma_f32_16x16x32_bf16(aw, af1, c1, 0, 0, 0);
#pragma unroll
    for (int i = 0; i < 4; ++i) {
      const int d = nt2 * 16 + quad * 4 + i;
      const float bv = Wcb[512 + d];
      Tw[d * 32 + lo]      = f2bf(c0[i] + bv);
      Tw[d * 32 + 16 + lo] = f2bf(c1[i] + bv);
    }
  }
  {
    const int ktq = (mbase >> 5) & 31;
    const size_t vb = ((size_t)b * 32 + ktq) * 8192;
#pragma unroll
    for (int it = 0; it < 16; ++it) {
      const int gsub = it * 64 + lane;
      *(u16x8*)&Vtt[vb + gsub * 8] = *(const u16x8*)&Tw[gsub * 8];
    }
  }
}

// ---------------- flash attention: barrier-free main loop, K/V from L2 ----------------
// 512 blocks x 256 thr, balanced pairs (tile p then 31-p), XCD-pinned by b.
// Wave split 2x2: kp = w&1 (kt parity), dh = w>>1 (output-dim half). Per-wave live
// state: qf 64 + O[4] 64 + Sx 16 regs -> fits 256-reg budget at 2 waves/SIMD,
// NO scratch spill (R2's failure: O[8]=128 regs overflowed -> 5 MB WRITE_SIZE).
// QK^T duplicated per dh group (MFMA is idle anyway). Partials additive (fixed SM_M);
// 2-way LDS combine per dh half; epilogue head GEMM on wave 0.
__global__ __launch_bounds__(256, 2) void attn_kernel(const unsigned short* __restrict__ Qb,
                                                      const unsigned short* __restrict__ Kb,
                                                      const unsigned short* __restrict__ Vtt,
                                                      const unsigned short* __restrict__ WfT,
                                                      const float* __restrict__ bfp,
                                                      const float* __restrict__ x,
                                                      const float* __restrict__ sgpart,
                                                      float* __restrict__ lsum,
                                                      unsigned int* __restrict__ total,
                                                      float* __restrict__ out) {
  __shared__ float CO0[4096];          // 32 rows x 128 dims (dh=0 partial from w1)
  __shared__ float CO1[4096];          // 32 rows x 128 dims (dh=1 partial from w3)
  __shared__ unsigned short OLs[8448]; // 32 x 264 bf16 normalized O (A-layout)
  __shared__ float OlL[4][32];
  __shared__ unsigned int flagv;
  const int g = blockIdx.x;
  const int b = (g & 7) * 4 + ((g >> 3) & 3);  // XCD (g%8) pinned: 4 batches per XCD
  const int p = g >> 5;                        // 0..15 -> tiles p and 31-p
  const int tid = threadIdx.x;
  const int w = tid >> 6, lane = tid & 63;
  const int kp = w & 1, dh = w >> 1;
  const int cl = lane & 31, hi = lane >> 5;

  const unsigned short* KbB = Kb + (size_t)b * 262144;
  const unsigned short* VtB = Vtt + (size_t)b * 262144;

  float S_ = 0.f, SS = 0.f;
#pragma unroll
  for (int i = 0; i < 8; ++i) {
    S_ += sgpart[(b * 8 + i) * 2];
    SS += sgpart[(b * 8 + i) * 2 + 1];
  }
  const float mean = S_ * (1.f / (float)L_SZ);
  const float var = (SS - S_ * mean) * (1.f / (float)(L_SZ - 1));
  const float invb = 1.f / (sqrtf(var) + 1e-5f);
  float lacc = 0.f;

#pragma unroll 1
  for (int half = 0; half < 2; ++half) {
    const int ti = half ? (31 - p) : p;
    const int qr0 = ti * 32;

    // Q fragments: lane cl = q row (B-operand of swapped QK)
    s16x8 qf[16];
    {
      const size_t qrow = ((size_t)b * 1024 + qr0 + cl) * 256;
#pragma unroll
      for (int cb = 0; cb < 16; ++cb)
        qf[cb] = *(const s16x8*)&Qb[qrow + cb * 16 + hi * 8];
    }

    f32x16 O[4];  // this wave's 128-dim half: dims [dh*128, dh*128+128)
#pragma unroll
    for (int i4 = 0; i4 < 4; ++i4)
#pragma unroll
      for (int i = 0; i < 16; ++i) O[i4][i] = 0.f;
    float Ol = 0.f;

    for (int kt = kp; kt <= ti; kt += 2) {
      // S^T[32t x 32q] = K_tile . Q^T  (A = K: lane cl = key row; B = Q: lane cl = q)
      const unsigned short* kp_ = KbB + (size_t)kt * 8192 + cl * 256 + hi * 8;
      f32x16 Sx;
#pragma unroll
      for (int i = 0; i < 16; ++i) Sx[i] = 0.f;
#pragma unroll
      for (int cb = 0; cb < 16; ++cb) {
        s16x8 kf = *(const s16x8*)&kp_[cb * 16];
        Sx = __builtin_amdgcn_mfma_f32_32x32x16_bf16(kf, qf[cb], Sx, 0, 0, 0);
      }
      // softmax numerator; C layout: col=q=cl, row=t=(r&3)+8(r>>2)+4hi
      float e[16];
      const bool diag = (kt == ti);
#pragma unroll
      for (int r = 0; r < 16; ++r) {
        const int trow = (r & 3) + 8 * (r >> 2) + 4 * hi;
        float ev = __expf(Sx[r] - SM_M);
        if (diag && trow > cl) ev = 0.f;
        e[r] = ev;
        Ol += ev;
      }
      // pack P^T column (this lane's q) into A-fragment words; exchange hi-halves
      u32 w8[8];
#pragma unroll
      for (int m = 0; m < 8; ++m)
        w8[m] = (u32)f2bf(e[2 * m]) | ((u32)f2bf(e[2 * m + 1]) << 16);
      const u32 r1 = (u32)__shfl_xor((int)(hi ? w8[0] : w8[2]), 32);
      const u32 r2 = (u32)__shfl_xor((int)(hi ? w8[1] : w8[3]), 32);
      const u32 r3 = (u32)__shfl_xor((int)(hi ? w8[4] : w8[6]), 32);
      const u32 r4 = (u32)__shfl_xor((int)(hi ? w8[5] : w8[7]), 32);
      union { u32x4 u; s16x8 s; } p0, p1;
      p0.u[0] = hi ? r1 : w8[0];
      p0.u[1] = hi ? r2 : w8[1];
      p0.u[2] = hi ? w8[2] : r1;
      p0.u[3] = hi ? w8[3] : r2;
      p1.u[0] = hi ? r3 : w8[4];
      p1.u[1] = hi ? r4 : w8[5];
      p1.u[2] = hi ? w8[6] : r3;
      p1.u[3] = hi ? w8[7] : r4;
      // PV on this wave's 128-dim half: B = V^T tile (lane cl = d_local)
      const unsigned short* vp = VtB + (size_t)kt * 8192 + (dh * 4) * 1024 + cl * 32 + hi * 8;
#pragma unroll
      for (int i4 = 0; i4 < 4; ++i4) {
        s16x8 v0 = *(const s16x8*)&vp[i4 * 1024];
        s16x8 v1 = *(const s16x8*)&vp[i4 * 1024 + 16];
        O[i4] = __builtin_amdgcn_mfma_f32_32x32x16_bf16(p0.s, v0, O[i4], 0, 0, 0);
        O[i4] = __builtin_amdgcn_mfma_f32_32x32x16_bf16(p1.s, v1, O[i4], 0, 0, 0);
      }
    }
    Ol += __shfl_xor(Ol, 32);  // both hi-halves of column q

    // ---- combine partials: 2-way per dh half ----
    __syncthreads();  // CO/OLs reuse guard vs previous half's epilogue
    if (w == 1) {
#pragma unroll
      for (int i4 = 0; i4 < 4; ++i4)
#pragma unroll
        for (int r = 0; r < 16; ++r) {
          const int row = (r & 3) + 8 * (r >> 2) + 4 * hi;
          CO0[row * 128 + i4 * 32 + cl] = O[i4][r];
        }
    }
    if (w == 3) {
#pragma unroll
      for (int i4 = 0; i4 < 4; ++i4)
#pragma unroll
        for (int r = 0; r < 16; ++r) {
          const int row = (r & 3) + 8 * (r >> 2) + 4 * hi;
          CO1[row * 128 + i4 * 32 + cl] = O[i4][r];
        }
    }
    if (hi == 0) OlL[w][cl] = Ol;
    __syncthreads();
    if (kp == 0) {  // waves 0 and 2: reduce, normalize, write bf16 A-layout half
      const float* CO = dh ? CO1 : CO0;
      float ivr[16];
#pragma unroll
      for (int r = 0; r < 16; ++r) {
        const int row = (r & 3) + 8 * (r >> 2) + 4 * hi;
        ivr[r] = 1.f / (OlL[0][row] + OlL[1][row]);
      }
#pragma unroll
      for (int i4 = 0; i4 < 4; ++i4)
#pragma unroll
        for (int r = 0; r < 16; ++r) {
          const int row = (r & 3) + 8 * (r >> 2) + 4 * hi;
          const float ov = O[i4][r] + CO[row * 128 + i4 * 32 + cl];
          OLs[row * 264 + (dh * 4 + i4) * 32 + cl] = f2bf(ov * ivr[r]);
        }
    }
    __syncthreads();
    if (w == 0) {
      // ---- epilogue (wave 0): head GEMM on full 256-d rows -> fused MSE ----
      s16x8 af[16];
#pragma unroll
      for (int cb = 0; cb < 16; ++cb)
        af[cb] = *(const s16x8*)&OLs[cl * 264 + cb * 16 + hi * 8];
      f32x16 hacc;
#pragma unroll
      for (int i = 0; i < 16; ++i) hacc[i] = 0.f;
#pragma unroll
      for (int cb = 0; cb < 16; ++cb) {
        s16x8 bfr = *(const s16x8*)&WfT[(size_t)cl * 256 + cb * 16 + hi * 8];
        hacc = __builtin_amdgcn_mfma_f32_32x32x16_bf16(af[cb], bfr, hacc, 0, 0, 0);
      }
      const float ba = bfp[cl];
#pragma unroll
      for (int r = 0; r < 16; ++r) {
        const int row = (r & 3) + 8 * (r >> 2) + 4 * hi;
        const int t = qr0 + row;
        if (t < 1023) {
          const float pr = hacc[r] + ba;
          const float tg = (x[(size_t)b * L_SZ + (t + 1) * 32 + cl] - mean) * invb;
          const float d = pr - tg;
          lacc += d * d;
        }
      }
    }
  }

  // ---- loss: only wave 0 holds contributions; reduce and finalize ----
#pragma unroll
  for (int off = 32; off >= 1; off >>= 1) lacc += __shfl_down(lacc, off);
  if (tid == 0) {
    atomicAdd(lsum, lacc);
    __threadfence();
    unsigned int prev = atomicAdd(total, 1u);
    flagv = (prev == 511u) ? 1u : 0u;
  }
  __syncthreads();
  if (flagv && tid == 0) {
    float tot = atomicAdd(lsum, 0.0f);  // device-scope read including all adds
    out[0] = tot * (1.f / (float)(B_SZ * (T_SZ - 1) * PS_SZ));
  }
}

extern "C" void kernel_launch(void* const* d_in, const int* in_sizes, int n_in,
                              void* d_out, int out_size, void* d_ws, size_t ws_size,
                              hipStream_t stream) {
  const float* x      = (const float*)d_in[0];
  const float* W_proj = (const float*)d_in[1];
  const float* b_proj = (const float*)d_in[2];
  const float* W_qkv  = (const float*)d_in[3];
  const float* b_qkv  = (const float*)d_in[4];
  const float* W_out  = (const float*)d_in[5];
  const float* b_out  = (const float*)d_in[6];
  const float* W_head = (const float*)d_in[7];
  const float* b_head = (const float*)d_in[8];
  float* out = (float*)d_out;
  char* ws = (char*)d_ws;

  unsigned short* Qb     = (unsigned short*)ws;
  unsigned short* Kb     = (unsigned short*)(ws + (16ull << 20));
  unsigned short* Vtt    = (unsigned short*)(ws + (32ull << 20));
  char* tail = ws + (48ull << 20);
  float*          Wcb    = (float*)tail;                        // 768 fp32 folded qkv bias
  unsigned short* WqT    = (unsigned short*)(tail + 4096);      // 768x32 bf16
  unsigned short* WfT    = (unsigned short*)(tail + 65536);     // 32x256 bf16
  float*          bfp    = (float*)(tail + 98304);              // 32 fp32
  float*          sgpart = (float*)(tail + 102400);             // 256x2 fp32
  unsigned int*   total  = (unsigned int*)(tail + 106496);      // 1 ctr
  float*          lsum   = (float*)(tail + 106496 + 64);        // 1 fp32

  prep_kernel<<<389, 256, 0, stream>>>(x, sgpart, W_proj, b_proj, W_qkv, b_qkv,
                                       W_out, b_out, W_head, b_head,
                                       Wcb, WqT, WfT, bfp, total, lsum);
  qkv_kernel<<<256, 256, 0, stream>>>(x, sgpart, WqT, Wcb, Qb, Kb, Vtt);
  attn_kernel<<<512, 256, 0, stream>>>(Qb, Kb, Vtt, WfT, bfp, x, sgpart, lsum, total, out);
}

// Round 4
// 190.996 us; speedup vs baseline: 1.1083x; 1.1083x over previous
//
#include <hip/hip_runtime.h>
#include <math.h>

#define B_SZ 32
#define L_SZ 32768
#define T_SZ 1024
#define PS_SZ 32
#define D_SZ 256
#define SM_M 10.0f   // static softmax max-shift; scores ~N(0,1), max << 10

typedef float f32x4 __attribute__((ext_vector_type(4)));
typedef float f32x16 __attribute__((ext_vector_type(16)));
typedef short s16x8 __attribute__((ext_vector_type(8)));
typedef unsigned short u16x8 __attribute__((ext_vector_type(8)));
typedef unsigned int u32;
typedef unsigned int u32x4 __attribute__((ext_vector_type(4)));

__device__ __forceinline__ unsigned short f2bf(float f) {
  union { float f; unsigned int u; } v; v.f = f;
  unsigned int r = v.u + 0x7FFFu + ((v.u >> 16) & 1u);
  return (unsigned short)(r >> 16);
}

__device__ __forceinline__ void g2l16(const unsigned short* g, unsigned short* l) {
  __builtin_amdgcn_global_load_lds(
      (const __attribute__((address_space(1))) unsigned int*)g,
      (__attribute__((address_space(3))) unsigned int*)l, 16, 0, 0);
}

// ---------------- prep: stats partials + weight folds + counter zero ----------------
__global__ __launch_bounds__(256) void prep_kernel(const float* __restrict__ x,
                                                   float* __restrict__ sgpart,
                                                   const float* __restrict__ Wp,
                                                   const float* __restrict__ bp,
                                                   const float* __restrict__ Wq,
                                                   const float* __restrict__ bq,
                                                   const float* __restrict__ Wo,
                                                   const float* __restrict__ bo,
                                                   const float* __restrict__ Wh,
                                                   const float* __restrict__ bh,
                                                   float* __restrict__ Wcb,
                                                   unsigned short* __restrict__ WqT,
                                                   unsigned short* __restrict__ WfT,
                                                   float* __restrict__ bfp,
                                                   unsigned int* __restrict__ total,
                                                   float* __restrict__ lsum) {
  __shared__ float red[8];
  const int g = blockIdx.x, tid = threadIdx.x;
  const int w = tid >> 6, lane = tid & 63;
  if (g < 256) {
    const int b = g >> 3;
    const float* p = x + (size_t)b * L_SZ + (size_t)(g & 7) * 4096;
    float s = 0.f, ss = 0.f;
#pragma unroll
    for (int i = 0; i < 4; ++i) {
      float4 f = ((const float4*)p)[tid + i * 256];
      s += f.x + f.y + f.z + f.w;
      ss += f.x * f.x + f.y * f.y + f.z * f.z + f.w * f.w;
    }
#pragma unroll
    for (int off = 32; off >= 1; off >>= 1) {
      s += __shfl_down(s, off);
      ss += __shfl_down(ss, off);
    }
    if (lane == 0) { red[w] = s; red[4 + w] = ss; }
    __syncthreads();
    if (tid == 0) {
      sgpart[g * 2]     = red[0] + red[1] + red[2] + red[3];
      sgpart[g * 2 + 1] = red[4] + red[5] + red[6] + red[7];
    }
  } else if (g < 388) {
    int idx = (g - 256) * 256 + tid;
    if (idx < 33 * 768) {
      int p = idx / 768, j = idx % 768;
      const float* arow = (p < 32) ? (Wp + p * 256) : bp;
      float acc = (p < 32) ? 0.f : bq[j];
      for (int d = 0; d < 256; ++d) acc += arow[d] * Wq[d * 768 + j];
      if (p < 32) WqT[j * 32 + p] = f2bf(acc);
      else Wcb[j] = acc;
    } else {
      int k = idx - 33 * 768;
      if (k < 8192) {
        int p = k >> 8, d = k & 255;
        float acc = 0.f;
        for (int e = 0; e < 256; ++e) acc += Wo[d * 256 + e] * Wh[e * 32 + p];
        WfT[p * 256 + d] = f2bf(acc);
      } else if (k < 8224) {
        int p = k - 8192;
        float acc = bh[p];
        for (int e = 0; e < 256; ++e) acc += bo[e] * Wh[e * 32 + p];
        bfp[p] = acc;
      }
    }
  } else {
    if (tid == 0) { total[0] = 0u; lsum[0] = 0.f; }
  }
}

// ---------------- qkv MFMA GEMM (verified R7/R9); V kt-tiled transposed ----------------
__global__ __launch_bounds__(256) void qkv_kernel(const float* __restrict__ x,
                                                  const float* __restrict__ sgpart,
                                                  const unsigned short* __restrict__ WqT,
                                                  const float* __restrict__ Wcb,
                                                  unsigned short* __restrict__ Qb,
                                                  unsigned short* __restrict__ Kb,
                                                  unsigned short* __restrict__ Vtt) {
  __shared__ unsigned short T4[4][8448];
  const int tid = threadIdx.x;
  const int w = tid >> 6, lane = tid & 63;
  const int lo = lane & 15, quad = lane >> 4;
  unsigned short* Tw = T4[w];
  const int mbase = blockIdx.x * 128 + w * 32;
  const int b = mbase >> 10;
  float S = 0.f, SS = 0.f;
#pragma unroll
  for (int i = 0; i < 8; ++i) {
    S += sgpart[(b * 8 + i) * 2];
    SS += sgpart[(b * 8 + i) * 2 + 1];
  }
  const float mean = S * (1.f / (float)L_SZ);
  const float var = (SS - S * mean) * (1.f / (float)(L_SZ - 1));
  const float inv = 1.f / (sqrtf(var) + 1e-5f);
  s16x8 af0, af1;
  {
    float4 a = *(const float4*)&x[(size_t)(mbase + lo) * 32 + quad * 8];
    float4 c = *(const float4*)&x[(size_t)(mbase + lo) * 32 + quad * 8 + 4];
    af0[0] = (short)f2bf((a.x - mean) * inv); af0[1] = (short)f2bf((a.y - mean) * inv);
    af0[2] = (short)f2bf((a.z - mean) * inv); af0[3] = (short)f2bf((a.w - mean) * inv);
    af0[4] = (short)f2bf((c.x - mean) * inv); af0[5] = (short)f2bf((c.y - mean) * inv);
    af0[6] = (short)f2bf((c.z - mean) * inv); af0[7] = (short)f2bf((c.w - mean) * inv);
    float4 d = *(const float4*)&x[(size_t)(mbase + 16 + lo) * 32 + quad * 8];
    float4 e = *(const float4*)&x[(size_t)(mbase + 16 + lo) * 32 + quad * 8 + 4];
    af1[0] = (short)f2bf((d.x - mean) * inv); af1[1] = (short)f2bf((d.y - mean) * inv);
    af1[2] = (short)f2bf((d.z - mean) * inv); af1[3] = (short)f2bf((d.w - mean) * inv);
    af1[4] = (short)f2bf((e.x - mean) * inv); af1[5] = (short)f2bf((e.y - mean) * inv);
    af1[6] = (short)f2bf((e.z - mean) * inv); af1[7] = (short)f2bf((e.w - mean) * inv);
  }
  // Q (pre-scaled 1/16)
#pragma unroll 4
  for (int nt = 0; nt < 16; ++nt) {
    s16x8 bf = *(const s16x8*)&WqT[(size_t)(nt * 16 + lo) * 32 + quad * 8];
    f32x4 c0 = {0.f, 0.f, 0.f, 0.f}, c1 = {0.f, 0.f, 0.f, 0.f};
    c0 = __builtin_amdgcn_mfma_f32_16x16x32_bf16(af0, bf, c0, 0, 0, 0);
    c1 = __builtin_amdgcn_mfma_f32_16x16x32_bf16(af1, bf, c1, 0, 0, 0);
    const int col = nt * 16 + lo;
    const float bi = Wcb[col];
#pragma unroll
    for (int i = 0; i < 4; ++i) {
      Tw[(quad * 4 + i) * 264 + col]      = f2bf((c0[i] + bi) * 0.0625f);
      Tw[(16 + quad * 4 + i) * 264 + col] = f2bf((c1[i] + bi) * 0.0625f);
    }
  }
#pragma unroll
  for (int it = 0; it < 16; ++it) {
    const int gsub = it * 64 + lane;
    const int row = gsub >> 5, c16 = gsub & 31;
    *(u16x8*)&Qb[(size_t)(mbase + row) * 256 + c16 * 8] =
        *(const u16x8*)&Tw[row * 264 + c16 * 8];
  }
  // K
#pragma unroll 4
  for (int nt = 0; nt < 16; ++nt) {
    s16x8 bf = *(const s16x8*)&WqT[(size_t)(256 + nt * 16 + lo) * 32 + quad * 8];
    f32x4 c0 = {0.f, 0.f, 0.f, 0.f}, c1 = {0.f, 0.f, 0.f, 0.f};
    c0 = __builtin_amdgcn_mfma_f32_16x16x32_bf16(af0, bf, c0, 0, 0, 0);
    c1 = __builtin_amdgcn_mfma_f32_16x16x32_bf16(af1, bf, c1, 0, 0, 0);
    const int col = nt * 16 + lo;
    const float bi = Wcb[256 + col];
#pragma unroll
    for (int i = 0; i < 4; ++i) {
      Tw[(quad * 4 + i) * 264 + col]      = f2bf(c0[i] + bi);
      Tw[(16 + quad * 4 + i) * 264 + col] = f2bf(c1[i] + bi);
    }
  }
#pragma unroll
  for (int it = 0; it < 16; ++it) {
    const int gsub = it * 64 + lane;
    const int row = gsub >> 5, c16 = gsub & 31;
    *(u16x8*)&Kb[(size_t)(mbase + row) * 256 + c16 * 8] =
        *(const u16x8*)&Tw[row * 264 + c16 * 8];
  }
  // V transposed, kt-tiled: Vtt[(b*32+ktq)*8192 + d*32 + t_local]
#pragma unroll 4
  for (int nt2 = 0; nt2 < 16; ++nt2) {
    s16x8 aw = *(const s16x8*)&WqT[(size_t)(512 + nt2 * 16 + lo) * 32 + quad * 8];
    f32x4 c0 = {0.f, 0.f, 0.f, 0.f}, c1 = {0.f, 0.f, 0.f, 0.f};
    c0 = __builtin_amdgcn_mfma_f32_16x16x32_bf16(aw, af0, c0, 0, 0, 0);
    c1 = __builtin_amdgcn_mfma_f32_16x16x32_bf16(aw, af1, c1, 0, 0, 0);
#pragma unroll
    for (int i = 0; i < 4; ++i) {
      const int d = nt2 * 16 + quad * 4 + i;
      const float bv = Wcb[512 + d];
      Tw[d * 32 + lo]      = f2bf(c0[i] + bv);
      Tw[d * 32 + 16 + lo] = f2bf(c1[i] + bv);
    }
  }
  {
    const int ktq = (mbase >> 5) & 31;
    const size_t vb = ((size_t)b * 32 + ktq) * 8192;
#pragma unroll
    for (int it = 0; it < 16; ++it) {
      const int gsub = it * 64 + lane;
      *(u16x8*)&Vtt[vb + gsub * 8] = *(const u16x8*)&Tw[gsub * 8];
    }
  }
}

// ---------------- flash attention: LDS-staged, dim-quarter waves ----------------
// 1024 blocks x 256 thr (one 32-row q-tile each), heavy-first, XCD-pinned by b.
// All 4 waves compute EVERY kt-step on the same tile; wave dh owns output dims
// [dh*64, dh*64+64): O[2] = 32 VGPRs. Live set qf(64)+O(32)+Sx(16) ~ 115 regs ->
// no spill/reload (R3 failure: 144+ live at 124 alloc -> per-step global reloads).
// K/V staged once per block via global_load_lds dbuf (L2-resident, 4MB/XCD);
// QK^T duplicated across waves (MFMA idle anyway) -> uniform waves, one barrier/step.
// Conflict-free LDS reads: K chunk^=(row&7), V tchunk^=((d>>1)&3); inverse swizzle
// applied on the GLOBAL source, LDS dest linear (both-sides-or-neither, m104/m231).
__global__ __launch_bounds__(256, 2) void attn_kernel(const unsigned short* __restrict__ Qb,
                                                      const unsigned short* __restrict__ Kb,
                                                      const unsigned short* __restrict__ Vtt,
                                                      const unsigned short* __restrict__ WfT,
                                                      const float* __restrict__ bfp,
                                                      const float* __restrict__ x,
                                                      const float* __restrict__ sgpart,
                                                      float* __restrict__ lsum,
                                                      unsigned int* __restrict__ total,
                                                      float* __restrict__ out) {
  __shared__ unsigned short SMEM[32768];  // 2 x (K 8192 | V 8192) shorts = 64 KB
  const int g = blockIdx.x;
  const int b = (g & 7) * 4 + ((g >> 3) & 3);  // XCD (g%8) pinned: 4 batches per XCD
  const int ti = 31 - (g >> 5);                // heavy-first (LPT packing)
  const int tid = threadIdx.x;
  const int w = tid >> 6, lane = tid & 63;
  const int dh = w;                            // wave = output-dim quarter
  const int cl = lane & 31, hi = lane >> 5;
  const int qr0 = ti * 32;
  const int nk = ti + 1;

  const unsigned short* KbB = Kb + (size_t)b * 262144;
  const unsigned short* VtB = Vtt + (size_t)b * 262144;

  // staging source offsets (inverse-swizzled, kt-invariant)
  int ksrc[4], vsrc[4];
#pragma unroll
  for (int it = 0; it < 4; ++it) {
    const int cid = it * 256 + tid;
    const int krow = cid >> 5, kc = cid & 31;
    ksrc[it] = krow * 256 + ((kc ^ (krow & 7)) * 8);
    const int vd = cid >> 2, vtc = cid & 3;
    vsrc[it] = vd * 32 + ((vtc ^ ((vd >> 1) & 3)) * 8);
  }
  const int ldw = w * 512;  // wave-uniform chunk base within each 2048-short slab

  // Q fragments: lane cl = q row (B-operand of swapped QK)
  s16x8 qf[16];
  {
    const size_t qrow = ((size_t)b * 1024 + qr0 + cl) * 256;
#pragma unroll
    for (int cb = 0; cb < 16; ++cb)
      qf[cb] = *(const s16x8*)&Qb[qrow + cb * 16 + hi * 8];
  }

  f32x16 O[2];  // 32 q-rows x 64 dims
#pragma unroll
  for (int i4 = 0; i4 < 2; ++i4)
#pragma unroll
    for (int i = 0; i < 16; ++i) O[i4][i] = 0.f;
  float Ol = 0.f;

  // prologue: stage tile 0 into buf 0
#pragma unroll
  for (int it = 0; it < 4; ++it) g2l16(KbB + ksrc[it], &SMEM[it * 2048 + ldw]);
#pragma unroll
  for (int it = 0; it < 4; ++it) g2l16(VtB + vsrc[it], &SMEM[8192 + it * 2048 + ldw]);

  // kt-invariant read addressing
  const int vsz = (cl >> 1) & 3;
  const int vc0 = (hi ^ vsz) * 8;
  const int vc1 = ((2 | hi) ^ vsz) * 8;
  const int vrow = (dh * 64 + cl) * 32;

  for (int kt = 0; kt < nk; ++kt) {
    __syncthreads();  // drains own vmcnt -> buf[kt&1] fully staged & visible
    const int cur = (kt & 1) << 14;
    if (kt + 1 < nk) {  // prefetch next tile into other buffer; lands during compute
      const int nxt = ((kt + 1) & 1) << 14;
      const unsigned short* ksp = KbB + (size_t)(kt + 1) * 8192;
      const unsigned short* vsp = VtB + (size_t)(kt + 1) * 8192;
#pragma unroll
      for (int it = 0; it < 4; ++it) g2l16(ksp + ksrc[it], &SMEM[nxt + it * 2048 + ldw]);
#pragma unroll
      for (int it = 0; it < 4; ++it)
        g2l16(vsp + vsrc[it], &SMEM[nxt + 8192 + it * 2048 + ldw]);
    }

    // S^T[32t x 32q] = K_tile . Q^T  (A = K from LDS: lane cl = key row)
    f32x16 Sx;
#pragma unroll
    for (int i = 0; i < 16; ++i) Sx[i] = 0.f;
    const int krow = cur + cl * 256;
#pragma unroll
    for (int cb = 0; cb < 16; ++cb) {
      const int ch = (((2 * cb + hi)) ^ (cl & 7)) * 8;
      s16x8 kf = *(const s16x8*)&SMEM[krow + ch];
      Sx = __builtin_amdgcn_mfma_f32_32x32x16_bf16(kf, qf[cb], Sx, 0, 0, 0);
    }
    // softmax numerator; C layout: col=q=cl, row=t=(r&3)+8(r>>2)+4hi
    float e[16];
    const bool diag = (kt == ti);
#pragma unroll
    for (int r = 0; r < 16; ++r) {
      const int trow = (r & 3) + 8 * (r >> 2) + 4 * hi;
      float ev = __expf(Sx[r] - SM_M);
      if (diag && trow > cl) ev = 0.f;
      e[r] = ev;
      Ol += ev;
    }
    // pack P^T column (this lane's q) into A-fragment words; exchange hi-halves
    u32 w8[8];
#pragma unroll
    for (int m = 0; m < 8; ++m)
      w8[m] = (u32)f2bf(e[2 * m]) | ((u32)f2bf(e[2 * m + 1]) << 16);
    const u32 r1 = (u32)__shfl_xor((int)(hi ? w8[0] : w8[2]), 32);
    const u32 r2 = (u32)__shfl_xor((int)(hi ? w8[1] : w8[3]), 32);
    const u32 r3 = (u32)__shfl_xor((int)(hi ? w8[4] : w8[6]), 32);
    const u32 r4 = (u32)__shfl_xor((int)(hi ? w8[5] : w8[7]), 32);
    union { u32x4 u; s16x8 s; } p0, p1;
    p0.u[0] = hi ? r1 : w8[0];
    p0.u[1] = hi ? r2 : w8[1];
    p0.u[2] = hi ? w8[2] : r1;
    p0.u[3] = hi ? w8[3] : r2;
    p1.u[0] = hi ? r3 : w8[4];
    p1.u[1] = hi ? r4 : w8[5];
    p1.u[2] = hi ? w8[6] : r3;
    p1.u[3] = hi ? w8[7] : r4;
    // PV on this wave's 64-dim quarter: B = V^T from LDS (lane cl = d_local)
    const int vb0 = cur + 8192 + vrow;
#pragma unroll
    for (int i4 = 0; i4 < 2; ++i4) {
      s16x8 v0 = *(const s16x8*)&SMEM[vb0 + i4 * 1024 + vc0];
      s16x8 v1 = *(const s16x8*)&SMEM[vb0 + i4 * 1024 + vc1];
      O[i4] = __builtin_amdgcn_mfma_f32_32x32x16_bf16(p0.s, v0, O[i4], 0, 0, 0);
      O[i4] = __builtin_amdgcn_mfma_f32_32x32x16_bf16(p1.s, v1, O[i4], 0, 0, 0);
    }
  }
  __syncthreads();  // all waves done with buffers before OLs overlay

  // ---- epilogue: normalize (wave-local denom) -> OLs A-layout -> head GEMM -> MSE ----
  Ol += __shfl_xor(Ol, 32);        // full denominator for q = cl (identical in all waves)
  unsigned short* OLs = SMEM;      // overlay buf0: 32 x 264 bf16
  float ivr[16];
#pragma unroll
  for (int r = 0; r < 16; ++r) {
    const int row = (r & 3) + 8 * (r >> 2) + 4 * hi;
    ivr[r] = 1.f / __shfl(Ol, row);  // lane 'row' holds denom(q=row)
  }
#pragma unroll
  for (int i4 = 0; i4 < 2; ++i4)
#pragma unroll
    for (int r = 0; r < 16; ++r) {
      const int row = (r & 3) + 8 * (r >> 2) + 4 * hi;
      OLs[row * 264 + dh * 64 + i4 * 32 + cl] = f2bf(O[i4][r] * ivr[r]);
    }
  __syncthreads();

  float lacc = 0.f;
  if (w == 0) {
    float S_ = 0.f, SS = 0.f;
#pragma unroll
    for (int i = 0; i < 8; ++i) {
      S_ += sgpart[(b * 8 + i) * 2];
      SS += sgpart[(b * 8 + i) * 2 + 1];
    }
    const float mean = S_ * (1.f / (float)L_SZ);
    const float var = (SS - S_ * mean) * (1.f / (float)(L_SZ - 1));
    const float invb = 1.f / (sqrtf(var) + 1e-5f);
    s16x8 af[16];
#pragma unroll
    for (int cb = 0; cb < 16; ++cb)
      af[cb] = *(const s16x8*)&OLs[cl * 264 + cb * 16 + hi * 8];
    f32x16 hacc;
#pragma unroll
    for (int i = 0; i < 16; ++i) hacc[i] = 0.f;
#pragma unroll
    for (int cb = 0; cb < 16; ++cb) {
      s16x8 bfr = *(const s16x8*)&WfT[(size_t)cl * 256 + cb * 16 + hi * 8];
      hacc = __builtin_amdgcn_mfma_f32_32x32x16_bf16(af[cb], bfr, hacc, 0, 0, 0);
    }
    const float ba = bfp[cl];
#pragma unroll
    for (int r = 0; r < 16; ++r) {
      const int row = (r & 3) + 8 * (r >> 2) + 4 * hi;
      const int t = qr0 + row;
      if (t < 1023) {
        const float pr = hacc[r] + ba;
        const float tg = (x[(size_t)b * L_SZ + (t + 1) * 32 + cl] - mean) * invb;
        const float d = pr - tg;
        lacc += d * d;
      }
    }
#pragma unroll
    for (int off = 32; off >= 1; off >>= 1) lacc += __shfl_down(lacc, off);
  }

  // ---- in-kernel loss finalize (device-scope counter pattern, verified R10) ----
  if (tid == 0) {
    atomicAdd(lsum, lacc);
    __threadfence();
    unsigned int prev = atomicAdd(total, 1u);
    if (prev == 1023u) {
      float tot = atomicAdd(lsum, 0.0f);  // device-scope read including all adds
      out[0] = tot * (1.f / (float)(B_SZ * (T_SZ - 1) * PS_SZ));
    }
  }
}

extern "C" void kernel_launch(void* const* d_in, const int* in_sizes, int n_in,
                              void* d_out, int out_size, void* d_ws, size_t ws_size,
                              hipStream_t stream) {
  const float* x      = (const float*)d_in[0];
  const float* W_proj = (const float*)d_in[1];
  const float* b_proj = (const float*)d_in[2];
  const float* W_qkv  = (const float*)d_in[3];
  const float* b_qkv  = (const float*)d_in[4];
  const float* W_out  = (const float*)d_in[5];
  const float* b_out  = (const float*)d_in[6];
  const float* W_head = (const float*)d_in[7];
  const float* b_head = (const float*)d_in[8];
  float* out = (float*)d_out;
  char* ws = (char*)d_ws;

  unsigned short* Qb     = (unsigned short*)ws;
  unsigned short* Kb     = (unsigned short*)(ws + (16ull << 20));
  unsigned short* Vtt    = (unsigned short*)(ws + (32ull << 20));
  char* tail = ws + (48ull << 20);
  float*          Wcb    = (float*)tail;                        // 768 fp32 folded qkv bias
  unsigned short* WqT    = (unsigned short*)(tail + 4096);      // 768x32 bf16
  unsigned short* WfT    = (unsigned short*)(tail + 65536);     // 32x256 bf16
  float*          bfp    = (float*)(tail + 98304);              // 32 fp32
  float*          sgpart = (float*)(tail + 102400);             // 256x2 fp32
  unsigned int*   total  = (unsigned int*)(tail + 106496);      // 1 ctr
  float*          lsum   = (float*)(tail + 106496 + 64);        // 1 fp32

  prep_kernel<<<389, 256, 0, stream>>>(x, sgpart, W_proj, b_proj, W_qkv, b_qkv,
                                       W_out, b_out, W_head, b_head,
                                       Wcb, WqT, WfT, bfp, total, lsum);
  qkv_kernel<<<256, 256, 0, stream>>>(x, sgpart, WqT, Wcb, Qb, Kb, Vtt);
  attn_kernel<<<1024, 256, 0, stream>>>(Qb, Kb, Vtt, WfT, bfp, x, sgpart, lsum, total, out);
}

// Round 5
// 181.247 us; speedup vs baseline: 1.1679x; 1.0538x over previous
//
#include <hip/hip_runtime.h>
#include <math.h>

#define B_SZ 32
#define L_SZ 32768
#define T_SZ 1024
#define PS_SZ 32
#define D_SZ 256
#define SM_M 10.0f   // static softmax max-shift; scores ~N(0,1), max << 10

typedef float f32x4 __attribute__((ext_vector_type(4)));
typedef float f32x16 __attribute__((ext_vector_type(16)));
typedef short s16x8 __attribute__((ext_vector_type(8)));
typedef unsigned short u16x8 __attribute__((ext_vector_type(8)));
typedef unsigned int u32;
typedef unsigned int u32x4 __attribute__((ext_vector_type(4)));

__device__ __forceinline__ unsigned short f2bf(float f) {
  union { float f; unsigned int u; } v; v.f = f;
  unsigned int r = v.u + 0x7FFFu + ((v.u >> 16) & 1u);
  return (unsigned short)(r >> 16);
}

__device__ __forceinline__ void g2l16(const unsigned short* g, unsigned short* l) {
  __builtin_amdgcn_global_load_lds(
      (const __attribute__((address_space(1))) unsigned int*)g,
      (__attribute__((address_space(3))) unsigned int*)l, 16, 0, 0);
}

// ---------------- prep: stats partials + weight folds + counter zero ----------------
__global__ __launch_bounds__(256) void prep_kernel(const float* __restrict__ x,
                                                   float* __restrict__ sgpart,
                                                   const float* __restrict__ Wp,
                                                   const float* __restrict__ bp,
                                                   const float* __restrict__ Wq,
                                                   const float* __restrict__ bq,
                                                   const float* __restrict__ Wo,
                                                   const float* __restrict__ bo,
                                                   const float* __restrict__ Wh,
                                                   const float* __restrict__ bh,
                                                   float* __restrict__ Wcb,
                                                   unsigned short* __restrict__ WqT,
                                                   unsigned short* __restrict__ WfT,
                                                   float* __restrict__ bfp,
                                                   unsigned int* __restrict__ total,
                                                   float* __restrict__ lsum) {
  __shared__ float red[8];
  const int g = blockIdx.x, tid = threadIdx.x;
  const int w = tid >> 6, lane = tid & 63;
  if (g < 256) {
    const int b = g >> 3;
    const float* p = x + (size_t)b * L_SZ + (size_t)(g & 7) * 4096;
    float s = 0.f, ss = 0.f;
#pragma unroll
    for (int i = 0; i < 4; ++i) {
      float4 f = ((const float4*)p)[tid + i * 256];
      s += f.x + f.y + f.z + f.w;
      ss += f.x * f.x + f.y * f.y + f.z * f.z + f.w * f.w;
    }
#pragma unroll
    for (int off = 32; off >= 1; off >>= 1) {
      s += __shfl_down(s, off);
      ss += __shfl_down(ss, off);
    }
    if (lane == 0) { red[w] = s; red[4 + w] = ss; }
    __syncthreads();
    if (tid == 0) {
      sgpart[g * 2]     = red[0] + red[1] + red[2] + red[3];
      sgpart[g * 2 + 1] = red[4] + red[5] + red[6] + red[7];
    }
  } else if (g < 388) {
    int idx = (g - 256) * 256 + tid;
    if (idx < 33 * 768) {
      int p = idx / 768, j = idx % 768;
      const float* arow = (p < 32) ? (Wp + p * 256) : bp;
      float acc = (p < 32) ? 0.f : bq[j];
      for (int d = 0; d < 256; ++d) acc += arow[d] * Wq[d * 768 + j];
      if (p < 32) WqT[j * 32 + p] = f2bf(acc);
      else Wcb[j] = acc;
    } else {
      int k = idx - 33 * 768;
      if (k < 8192) {
        int p = k >> 8, d = k & 255;
        float acc = 0.f;
        for (int e = 0; e < 256; ++e) acc += Wo[d * 256 + e] * Wh[e * 32 + p];
        WfT[p * 256 + d] = f2bf(acc);
      } else if (k < 8224) {
        int p = k - 8192;
        float acc = bh[p];
        for (int e = 0; e < 256; ++e) acc += bo[e] * Wh[e * 32 + p];
        bfp[p] = acc;
      }
    }
  } else {
    if (tid == 0) { total[0] = 0u; lsum[0] = 0.f; }
  }
}

// ---------------- qkv MFMA GEMM (verified R7/R9); V kt-tiled transposed ----------------
__global__ __launch_bounds__(256) void qkv_kernel(const float* __restrict__ x,
                                                  const float* __restrict__ sgpart,
                                                  const unsigned short* __restrict__ WqT,
                                                  const float* __restrict__ Wcb,
                                                  unsigned short* __restrict__ Qb,
                                                  unsigned short* __restrict__ Kb,
                                                  unsigned short* __restrict__ Vtt) {
  __shared__ unsigned short T4[4][8448];
  const int tid = threadIdx.x;
  const int w = tid >> 6, lane = tid & 63;
  const int lo = lane & 15, quad = lane >> 4;
  unsigned short* Tw = T4[w];
  const int mbase = blockIdx.x * 128 + w * 32;
  const int b = mbase >> 10;
  float S = 0.f, SS = 0.f;
#pragma unroll
  for (int i = 0; i < 8; ++i) {
    S += sgpart[(b * 8 + i) * 2];
    SS += sgpart[(b * 8 + i) * 2 + 1];
  }
  const float mean = S * (1.f / (float)L_SZ);
  const float var = (SS - S * mean) * (1.f / (float)(L_SZ - 1));
  const float inv = 1.f / (sqrtf(var) + 1e-5f);
  s16x8 af0, af1;
  {
    float4 a = *(const float4*)&x[(size_t)(mbase + lo) * 32 + quad * 8];
    float4 c = *(const float4*)&x[(size_t)(mbase + lo) * 32 + quad * 8 + 4];
    af0[0] = (short)f2bf((a.x - mean) * inv); af0[1] = (short)f2bf((a.y - mean) * inv);
    af0[2] = (short)f2bf((a.z - mean) * inv); af0[3] = (short)f2bf((a.w - mean) * inv);
    af0[4] = (short)f2bf((c.x - mean) * inv); af0[5] = (short)f2bf((c.y - mean) * inv);
    af0[6] = (short)f2bf((c.z - mean) * inv); af0[7] = (short)f2bf((c.w - mean) * inv);
    float4 d = *(const float4*)&x[(size_t)(mbase + 16 + lo) * 32 + quad * 8];
    float4 e = *(const float4*)&x[(size_t)(mbase + 16 + lo) * 32 + quad * 8 + 4];
    af1[0] = (short)f2bf((d.x - mean) * inv); af1[1] = (short)f2bf((d.y - mean) * inv);
    af1[2] = (short)f2bf((d.z - mean) * inv); af1[3] = (short)f2bf((d.w - mean) * inv);
    af1[4] = (short)f2bf((e.x - mean) * inv); af1[5] = (short)f2bf((e.y - mean) * inv);
    af1[6] = (short)f2bf((e.z - mean) * inv); af1[7] = (short)f2bf((e.w - mean) * inv);
  }
  // Q (pre-scaled 1/16)
#pragma unroll 4
  for (int nt = 0; nt < 16; ++nt) {
    s16x8 bf = *(const s16x8*)&WqT[(size_t)(nt * 16 + lo) * 32 + quad * 8];
    f32x4 c0 = {0.f, 0.f, 0.f, 0.f}, c1 = {0.f, 0.f, 0.f, 0.f};
    c0 = __builtin_amdgcn_mfma_f32_16x16x32_bf16(af0, bf, c0, 0, 0, 0);
    c1 = __builtin_amdgcn_mfma_f32_16x16x32_bf16(af1, bf, c1, 0, 0, 0);
    const int col = nt * 16 + lo;
    const float bi = Wcb[col];
#pragma unroll
    for (int i = 0; i < 4; ++i) {
      Tw[(quad * 4 + i) * 264 + col]      = f2bf((c0[i] + bi) * 0.0625f);
      Tw[(16 + quad * 4 + i) * 264 + col] = f2bf((c1[i] + bi) * 0.0625f);
    }
  }
#pragma unroll
  for (int it = 0; it < 16; ++it) {
    const int gsub = it * 64 + lane;
    const int row = gsub >> 5, c16 = gsub & 31;
    *(u16x8*)&Qb[(size_t)(mbase + row) * 256 + c16 * 8] =
        *(const u16x8*)&Tw[row * 264 + c16 * 8];
  }
  // K
#pragma unroll 4
  for (int nt = 0; nt < 16; ++nt) {
    s16x8 bf = *(const s16x8*)&WqT[(size_t)(256 + nt * 16 + lo) * 32 + quad * 8];
    f32x4 c0 = {0.f, 0.f, 0.f, 0.f}, c1 = {0.f, 0.f, 0.f, 0.f};
    c0 = __builtin_amdgcn_mfma_f32_16x16x32_bf16(af0, bf, c0, 0, 0, 0);
    c1 = __builtin_amdgcn_mfma_f32_16x16x32_bf16(af1, bf, c1, 0, 0, 0);
    const int col = nt * 16 + lo;
    const float bi = Wcb[256 + col];
#pragma unroll
    for (int i = 0; i < 4; ++i) {
      Tw[(quad * 4 + i) * 264 + col]      = f2bf(c0[i] + bi);
      Tw[(16 + quad * 4 + i) * 264 + col] = f2bf(c1[i] + bi);
    }
  }
#pragma unroll
  for (int it = 0; it < 16; ++it) {
    const int gsub = it * 64 + lane;
    const int row = gsub >> 5, c16 = gsub & 31;
    *(u16x8*)&Kb[(size_t)(mbase + row) * 256 + c16 * 8] =
        *(const u16x8*)&Tw[row * 264 + c16 * 8];
  }
  // V transposed, kt-tiled: Vtt[(b*32+ktq)*8192 + d*32 + t_local]
#pragma unroll 4
  for (int nt2 = 0; nt2 < 16; ++nt2) {
    s16x8 aw = *(const s16x8*)&WqT[(size_t)(512 + nt2 * 16 + lo) * 32 + quad * 8];
    f32x4 c0 = {0.f, 0.f, 0.f, 0.f}, c1 = {0.f, 0.f, 0.f, 0.f};
    c0 = __builtin_amdgcn_mfma_f32_16x16x32_bf16(aw, af0, c0, 0, 0, 0);
    c1 = __builtin_amdgcn_mfma_f32_16x16x32_bf16(aw, af1, c1, 0, 0, 0);
#pragma unroll
    for (int i = 0; i < 4; ++i) {
      const int d = nt2 * 16 + quad * 4 + i;
      const float bv = Wcb[512 + d];
      Tw[d * 32 + lo]      = f2bf(c0[i] + bv);
      Tw[d * 32 + 16 + lo] = f2bf(c1[i] + bv);
    }
  }
  {
    const int ktq = (mbase >> 5) & 31;
    const size_t vb = ((size_t)b * 32 + ktq) * 8192;
#pragma unroll
    for (int it = 0; it < 16; ++it) {
      const int gsub = it * 64 + lane;
      *(u16x8*)&Vtt[vb + gsub * 8] = *(const u16x8*)&Tw[gsub * 8];
    }
  }
}

// ------------- flash attention: depth-3 counted-vmcnt ring (T3/T4), uniform blocks -------------
// 256 blocks x 512 thr (8 waves), 1 block/CU (LDS 128KB = 4-slot ring x (K 16K | V 16K)).
// Block = (b XCD-pinned, pair p): runs group p (tiles 2p,2p+1; nk=2p+2) then group 15-p
// (nk=32-2p) -> 34 steps for EVERY block. Waves: th = w&1 (tile), dq = w>>2.. w>>1 (dim
// quarter). Per-wave: qf 64 + O[2] 32 regs -> no spill (R2) / no reload (R3).
// Step: s_waitcnt vmcnt(8) [loads for kt+1,kt+2 STAY IN FLIGHT across the barrier],
// s_barrier, sched_barrier, STAGE(kt+3), compute. Load latency covered by 3 steps
// (R0/R4 failure: depth-2 forces vmcnt(0) drain every step -> ~7k cyc/step exposed).
// Swizzles (empirical, R1-measured 0 conflicts): K chunk col = j ^ row (full xor);
// V t-chunk col = tc ^ ((d>>2)&3)  [NOT (d>>1): that variant = R0/R4's 2.4-5.4M conflicts].
// Inverse applied on GLOBAL source, LDS dest linear (both-sides-or-neither, m104/m231).
// Phase-A normalized O parked in its own (dead) Qb rows; final epilogue: 4 head GEMMs + MSE.
__global__ __launch_bounds__(512, 2) void attn_kernel(const unsigned short* __restrict__ Qb,
                                                      const unsigned short* __restrict__ Kb,
                                                      const unsigned short* __restrict__ Vtt,
                                                      const unsigned short* __restrict__ WfT,
                                                      const float* __restrict__ bfp,
                                                      const float* __restrict__ x,
                                                      const float* __restrict__ sgpart,
                                                      float* __restrict__ lsum,
                                                      unsigned int* __restrict__ total,
                                                      float* __restrict__ out) {
  __shared__ unsigned short SMEM[65536];  // 4 ring slots x 16384 shorts
  __shared__ float redf[8];
  const int g = blockIdx.x;
  const int b = (g & 7) * 4 + ((g >> 3) & 3);  // XCD (g%8) pinned: 4 batches per XCD
  const int p = g >> 5;                        // 0..7 -> groups p and 15-p
  const int tid = threadIdx.x;
  const int w = tid >> 6, lane = tid & 63;
  const int th = w & 1, dq = w >> 1;           // tile-in-group, dim quarter
  const int cl = lane & 31, hi = lane >> 5;

  const unsigned short* KbB = Kb + (size_t)b * 262144;
  const unsigned short* VtB = Vtt + (size_t)b * 262144;
  unsigned short* QbM = (unsigned short*)Qb;

  // staging: thread covers chunks c0=tid, c1=512+tid of each 1024-chunk K/V tile.
  // source inverse-swizzled; dest linear (wave-uniform base, lane*16B implicit).
  const int c0 = tid, c1 = 512 + tid;
  const int ks0 = (c0 >> 5) * 256 + (((c0 & 31) ^ (c0 >> 5)) * 8);
  const int ks1 = (c1 >> 5) * 256 + (((c1 & 31) ^ (c1 >> 5)) * 8);
  const int vs0 = (c0 >> 2) * 32 + (((c0 & 3) ^ ((c0 >> 4) & 3)) * 8);
  const int vs1 = (c1 >> 2) * 32 + (((c1 & 3) ^ ((c1 >> 4) & 3)) * 8);
  const int kd0 = w * 512, kd1 = 4096 + w * 512;

  auto STAGE = [&](int t) {
    const unsigned short* kg = KbB + (size_t)t * 8192;
    const unsigned short* vg = VtB + (size_t)t * 8192;
    unsigned short* Lb = &SMEM[(t & 3) * 16384];
    g2l16(kg + ks0, Lb + kd0);
    g2l16(kg + ks1, Lb + kd1);
    g2l16(vg + vs0, Lb + 8192 + kd0);
    g2l16(vg + vs1, Lb + 8192 + kd1);
  };

  s16x8 qf[16];
  f32x16 O0, O1;
  float Ol = 0.f;
  const int vsz = (cl >> 2) & 3;
  const int cva = (hi ^ vsz) * 8, cvb = (((2 | hi)) ^ vsz) * 8;

  auto run_phase = [&](int gph) {
    const int nk = 2 * gph + 2;
    const int myti = 2 * gph + th;
    const size_t qrow = ((size_t)b * 1024 + myti * 32 + cl) * 256;
#pragma unroll
    for (int cb = 0; cb < 16; ++cb) qf[cb] = *(const s16x8*)&Qb[qrow + cb * 16 + hi * 8];
#pragma unroll
    for (int i = 0; i < 16; ++i) { O0[i] = 0.f; O1[i] = 0.f; }
    Ol = 0.f;
    const int npre = nk < 3 ? nk : 3;
    for (int s = 0; s < npre; ++s) STAGE(s);
    for (int s = 0; s < nk; ++s) {
      const int rem = nk - 1 - s;
      if (rem >= 2)      asm volatile("s_waitcnt vmcnt(8)" ::: "memory");
      else if (rem == 1) asm volatile("s_waitcnt vmcnt(4)" ::: "memory");
      else               asm volatile("s_waitcnt vmcnt(0)" ::: "memory");
      __builtin_amdgcn_s_barrier();
      __builtin_amdgcn_sched_barrier(0);
      if (s + 3 < nk) STAGE(s + 3);
      if (s <= myti) {
        const unsigned short* Lk = &SMEM[(s & 3) * 16384];
        f32x16 Sx;
#pragma unroll
        for (int i = 0; i < 16; ++i) Sx[i] = 0.f;
#pragma unroll
        for (int cb = 0; cb < 16; ++cb) {
          const int ch = (2 * cb + hi) ^ cl;
          s16x8 kf = *(const s16x8*)&Lk[cl * 256 + ch * 8];
          Sx = __builtin_amdgcn_mfma_f32_32x32x16_bf16(kf, qf[cb], Sx, 0, 0, 0);
        }
        float e[16];
        const bool diag = (s == myti);
#pragma unroll
        for (int r = 0; r < 16; ++r) {
          const int trow = (r & 3) + 8 * (r >> 2) + 4 * hi;
          float ev = __expf(Sx[r] - SM_M);
          if (diag && trow > cl) ev = 0.f;
          e[r] = ev;
          Ol += ev;
        }
        u32 w8[8];
#pragma unroll
        for (int m = 0; m < 8; ++m)
          w8[m] = (u32)f2bf(e[2 * m]) | ((u32)f2bf(e[2 * m + 1]) << 16);
        const u32 r1 = (u32)__shfl_xor((int)(hi ? w8[0] : w8[2]), 32);
        const u32 r2 = (u32)__shfl_xor((int)(hi ? w8[1] : w8[3]), 32);
        const u32 r3 = (u32)__shfl_xor((int)(hi ? w8[4] : w8[6]), 32);
        const u32 r4 = (u32)__shfl_xor((int)(hi ? w8[5] : w8[7]), 32);
        union { u32x4 u; s16x8 s; } p0, p1;
        p0.u[0] = hi ? r1 : w8[0];
        p0.u[1] = hi ? r2 : w8[1];
        p0.u[2] = hi ? w8[2] : r1;
        p0.u[3] = hi ? w8[3] : r2;
        p1.u[0] = hi ? r3 : w8[4];
        p1.u[1] = hi ? r4 : w8[5];
        p1.u[2] = hi ? w8[6] : r3;
        p1.u[3] = hi ? w8[7] : r4;
        const unsigned short* Lv = &SMEM[(s & 3) * 16384 + 8192];
        const int d0 = (dq * 64 + cl) * 32, d1 = (dq * 64 + 32 + cl) * 32;
        s16x8 v0 = *(const s16x8*)&Lv[d0 + cva];
        s16x8 v1 = *(const s16x8*)&Lv[d0 + cvb];
        O0 = __builtin_amdgcn_mfma_f32_32x32x16_bf16(p0.s, v0, O0, 0, 0, 0);
        O0 = __builtin_amdgcn_mfma_f32_32x32x16_bf16(p1.s, v1, O0, 0, 0, 0);
        s16x8 v2 = *(const s16x8*)&Lv[d1 + cva];
        s16x8 v3 = *(const s16x8*)&Lv[d1 + cvb];
        O1 = __builtin_amdgcn_mfma_f32_32x32x16_bf16(p0.s, v2, O1, 0, 0, 0);
        O1 = __builtin_amdgcn_mfma_f32_32x32x16_bf16(p1.s, v3, O1, 0, 0, 0);
      }
    }
    Ol += __shfl_xor(Ol, 32);  // full denominator for q = cl
  };

  // ---- phase A: group p; park normalized O in this block's (dead) Qb rows ----
  run_phase(p);
  {
    float ivr[16];
#pragma unroll
    for (int r = 0; r < 16; ++r) {
      const int row = (r & 3) + 8 * (r >> 2) + 4 * hi;
      ivr[r] = 1.f / __shfl(Ol, row);
    }
    const size_t obase = ((size_t)b * 1024 + (2 * p + th) * 32) * 256;
#pragma unroll
    for (int r = 0; r < 16; ++r) {
      const int row = (r & 3) + 8 * (r >> 2) + 4 * hi;
      QbM[obase + row * 256 + dq * 64 + cl]      = f2bf(O0[r] * ivr[r]);
      QbM[obase + row * 256 + dq * 64 + 32 + cl] = f2bf(O1[r] * ivr[r]);
    }
  }
  asm volatile("s_waitcnt vmcnt(0)" ::: "memory");  // drain O-park stores + stray prefetch
  __builtin_amdgcn_s_barrier();                     // ring slots free for phase B

  // ---- phase B: group 15-p ----
  run_phase(15 - p);
  __syncthreads();  // all ring reads done; SMEM free for OLs overlay

  unsigned short* OLs = SMEM;  // 64 x 264 bf16 (rows th*32+row)
  {
    float ivr[16];
#pragma unroll
    for (int r = 0; r < 16; ++r) {
      const int row = (r & 3) + 8 * (r >> 2) + 4 * hi;
      ivr[r] = 1.f / __shfl(Ol, row);
    }
#pragma unroll
    for (int r = 0; r < 16; ++r) {
      const int row = (r & 3) + 8 * (r >> 2) + 4 * hi;
      OLs[(th * 32 + row) * 264 + dq * 64 + cl]      = f2bf(O0[r] * ivr[r]);
      OLs[(th * 32 + row) * 264 + dq * 64 + 32 + cl] = f2bf(O1[r] * ivr[r]);
    }
  }
  __syncthreads();

  // ---- epilogue: 4 head GEMMs (waves 0..3, one 32-row tile each) + fused MSE ----
  float lacc = 0.f;
  if (w < 4) {
    const int tile = (w == 0) ? 2 * p : (w == 1) ? 2 * p + 1
                   : (w == 2) ? 30 - 2 * p : 31 - 2 * p;
    s16x8 af[16];
    if (w < 2) {
      const size_t abase = ((size_t)b * 1024 + tile * 32 + cl) * 256;
#pragma unroll
      for (int cb = 0; cb < 16; ++cb)
        af[cb] = *(const s16x8*)&QbM[abase + cb * 16 + hi * 8];
    } else {
      const int sub = w - 2;
#pragma unroll
      for (int cb = 0; cb < 16; ++cb)
        af[cb] = *(const s16x8*)&OLs[(sub * 32 + cl) * 264 + cb * 16 + hi * 8];
    }
    f32x16 hacc;
#pragma unroll
    for (int i = 0; i < 16; ++i) hacc[i] = 0.f;
#pragma unroll
    for (int cb = 0; cb < 16; ++cb) {
      s16x8 bfr = *(const s16x8*)&WfT[(size_t)cl * 256 + cb * 16 + hi * 8];
      hacc = __builtin_amdgcn_mfma_f32_32x32x16_bf16(af[cb], bfr, hacc, 0, 0, 0);
    }
    float S_ = 0.f, SS = 0.f;
#pragma unroll
    for (int i = 0; i < 8; ++i) {
      S_ += sgpart[(b * 8 + i) * 2];
      SS += sgpart[(b * 8 + i) * 2 + 1];
    }
    const float mean = S_ * (1.f / (float)L_SZ);
    const float var = (SS - S_ * mean) * (1.f / (float)(L_SZ - 1));
    const float invb = 1.f / (sqrtf(var) + 1e-5f);
    const float ba = bfp[cl];
#pragma unroll
    for (int r = 0; r < 16; ++r) {
      const int row = (r & 3) + 8 * (r >> 2) + 4 * hi;
      const int t = tile * 32 + row;
      if (t < 1023) {
        const float pr = hacc[r] + ba;
        const float tg = (x[(size_t)b * L_SZ + (t + 1) * 32 + cl] - mean) * invb;
        const float d = pr - tg;
        lacc += d * d;
      }
    }
#pragma unroll
    for (int off = 32; off >= 1; off >>= 1) lacc += __shfl_down(lacc, off);
  }
  if (lane == 0) redf[w] = lacc;
  __syncthreads();

  // ---- in-kernel loss finalize (device-scope counter pattern, verified R10) ----
  if (tid == 0) {
    atomicAdd(lsum, redf[0] + redf[1] + redf[2] + redf[3]);
    __threadfence();
    unsigned int prev = atomicAdd(total, 1u);
    if (prev == 255u) {
      float tot = atomicAdd(lsum, 0.0f);  // device-scope read including all adds
      out[0] = tot * (1.f / (float)(B_SZ * (T_SZ - 1) * PS_SZ));
    }
  }
}

extern "C" void kernel_launch(void* const* d_in, const int* in_sizes, int n_in,
                              void* d_out, int out_size, void* d_ws, size_t ws_size,
                              hipStream_t stream) {
  const float* x      = (const float*)d_in[0];
  const float* W_proj = (const float*)d_in[1];
  const float* b_proj = (const float*)d_in[2];
  const float* W_qkv  = (const float*)d_in[3];
  const float* b_qkv  = (const float*)d_in[4];
  const float* W_out  = (const float*)d_in[5];
  const float* b_out  = (const float*)d_in[6];
  const float* W_head = (const float*)d_in[7];
  const float* b_head = (const float*)d_in[8];
  float* out = (float*)d_out;
  char* ws = (char*)d_ws;

  unsigned short* Qb     = (unsigned short*)ws;
  unsigned short* Kb     = (unsigned short*)(ws + (16ull << 20));
  unsigned short* Vtt    = (unsigned short*)(ws + (32ull << 20));
  char* tail = ws + (48ull << 20);
  float*          Wcb    = (float*)tail;                        // 768 fp32 folded qkv bias
  unsigned short* WqT    = (unsigned short*)(tail + 4096);      // 768x32 bf16
  unsigned short* WfT    = (unsigned short*)(tail + 65536);     // 32x256 bf16
  float*          bfp    = (float*)(tail + 98304);              // 32 fp32
  float*          sgpart = (float*)(tail + 102400);             // 256x2 fp32
  unsigned int*   total  = (unsigned int*)(tail + 106496);      // 1 ctr
  float*          lsum   = (float*)(tail + 106496 + 64);        // 1 fp32

  prep_kernel<<<389, 256, 0, stream>>>(x, sgpart, W_proj, b_proj, W_qkv, b_qkv,
                                       W_out, b_out, W_head, b_head,
                                       Wcb, WqT, WfT, bfp, total, lsum);
  qkv_kernel<<<256, 256, 0, stream>>>(x, sgpart, WqT, Wcb, Qb, Kb, Vtt);
  attn_kernel<<<256, 512, 0, stream>>>(Qb, Kb, Vtt, WfT, bfp, x, sgpart, lsum, total, out);
}

// Round 6
// 171.860 us; speedup vs baseline: 1.2317x; 1.0546x over previous
//
#include <hip/hip_runtime.h>
#include <math.h>

#define B_SZ 32
#define L_SZ 32768
#define T_SZ 1024
#define PS_SZ 32
#define D_SZ 256
#define SM_M 10.0f   // static softmax max-shift; scores ~N(0,1), max << 10

typedef float f32x4 __attribute__((ext_vector_type(4)));
typedef float f32x16 __attribute__((ext_vector_type(16)));
typedef short s16x8 __attribute__((ext_vector_type(8)));
typedef unsigned short u16x8 __attribute__((ext_vector_type(8)));
typedef unsigned int u32;
typedef unsigned int u32x2 __attribute__((ext_vector_type(2)));
typedef unsigned int u32x4 __attribute__((ext_vector_type(4)));

__device__ __forceinline__ unsigned short f2bf(float f) {
  union { float f; unsigned int u; } v; v.f = f;
  unsigned int r = v.u + 0x7FFFu + ((v.u >> 16) & 1u);
  return (unsigned short)(r >> 16);
}

__device__ __forceinline__ void g2l16(const unsigned short* g, unsigned short* l) {
  __builtin_amdgcn_global_load_lds(
      (const __attribute__((address_space(1))) unsigned int*)g,
      (__attribute__((address_space(3))) unsigned int*)l, 16, 0, 0);
}

// ---------------- prep: stats partials + weight folds + counter zero ----------------
__global__ __launch_bounds__(256) void prep_kernel(const float* __restrict__ x,
                                                   float* __restrict__ sgpart,
                                                   const float* __restrict__ Wp,
                                                   const float* __restrict__ bp,
                                                   const float* __restrict__ Wq,
                                                   const float* __restrict__ bq,
                                                   const float* __restrict__ Wo,
                                                   const float* __restrict__ bo,
                                                   const float* __restrict__ Wh,
                                                   const float* __restrict__ bh,
                                                   float* __restrict__ Wcb,
                                                   unsigned short* __restrict__ WqT,
                                                   unsigned short* __restrict__ WfT,
                                                   float* __restrict__ bfp,
                                                   unsigned int* __restrict__ total,
                                                   float* __restrict__ lsum) {
  __shared__ float red[8];
  const int g = blockIdx.x, tid = threadIdx.x;
  const int w = tid >> 6, lane = tid & 63;
  if (g < 256) {
    const int b = g >> 3;
    const float* p = x + (size_t)b * L_SZ + (size_t)(g & 7) * 4096;
    float s = 0.f, ss = 0.f;
#pragma unroll
    for (int i = 0; i < 4; ++i) {
      float4 f = ((const float4*)p)[tid + i * 256];
      s += f.x + f.y + f.z + f.w;
      ss += f.x * f.x + f.y * f.y + f.z * f.z + f.w * f.w;
    }
#pragma unroll
    for (int off = 32; off >= 1; off >>= 1) {
      s += __shfl_down(s, off);
      ss += __shfl_down(ss, off);
    }
    if (lane == 0) { red[w] = s; red[4 + w] = ss; }
    __syncthreads();
    if (tid == 0) {
      sgpart[g * 2]     = red[0] + red[1] + red[2] + red[3];
      sgpart[g * 2 + 1] = red[4] + red[5] + red[6] + red[7];
    }
  } else if (g < 388) {
    int idx = (g - 256) * 256 + tid;
    if (idx < 33 * 768) {
      int p = idx / 768, j = idx % 768;
      const float* arow = (p < 32) ? (Wp + p * 256) : bp;
      float acc = (p < 32) ? 0.f : bq[j];
      for (int d = 0; d < 256; ++d) acc += arow[d] * Wq[d * 768 + j];
      if (p < 32) WqT[j * 32 + p] = f2bf(acc);
      else Wcb[j] = acc;
    } else {
      int k = idx - 33 * 768;
      if (k < 8192) {
        int p = k >> 8, d = k & 255;
        float acc = 0.f;
        for (int e = 0; e < 256; ++e) acc += Wo[d * 256 + e] * Wh[e * 32 + p];
        WfT[p * 256 + d] = f2bf(acc);
      } else if (k < 8224) {
        int p = k - 8192;
        float acc = bh[p];
        for (int e = 0; e < 256; ++e) acc += bo[e] * Wh[e * 32 + p];
        bfp[p] = acc;
      }
    }
  } else {
    if (tid == 0) { total[0] = 0u; lsum[0] = 0.f; }
  }
}

// ---------------- qkv MFMA GEMM (verified R7/R9); V kt-tiled transposed ----------------
__global__ __launch_bounds__(256) void qkv_kernel(const float* __restrict__ x,
                                                  const float* __restrict__ sgpart,
                                                  const unsigned short* __restrict__ WqT,
                                                  const float* __restrict__ Wcb,
                                                  unsigned short* __restrict__ Qb,
                                                  unsigned short* __restrict__ Kb,
                                                  unsigned short* __restrict__ Vtt) {
  __shared__ unsigned short T4[4][8448];
  const int tid = threadIdx.x;
  const int w = tid >> 6, lane = tid & 63;
  const int lo = lane & 15, quad = lane >> 4;
  unsigned short* Tw = T4[w];
  const int mbase = blockIdx.x * 128 + w * 32;
  const int b = mbase >> 10;
  float S = 0.f, SS = 0.f;
#pragma unroll
  for (int i = 0; i < 8; ++i) {
    S += sgpart[(b * 8 + i) * 2];
    SS += sgpart[(b * 8 + i) * 2 + 1];
  }
  const float mean = S * (1.f / (float)L_SZ);
  const float var = (SS - S * mean) * (1.f / (float)(L_SZ - 1));
  const float inv = 1.f / (sqrtf(var) + 1e-5f);
  s16x8 af0, af1;
  {
    float4 a = *(const float4*)&x[(size_t)(mbase + lo) * 32 + quad * 8];
    float4 c = *(const float4*)&x[(size_t)(mbase + lo) * 32 + quad * 8 + 4];
    af0[0] = (short)f2bf((a.x - mean) * inv); af0[1] = (short)f2bf((a.y - mean) * inv);
    af0[2] = (short)f2bf((a.z - mean) * inv); af0[3] = (short)f2bf((a.w - mean) * inv);
    af0[4] = (short)f2bf((c.x - mean) * inv); af0[5] = (short)f2bf((c.y - mean) * inv);
    af0[6] = (short)f2bf((c.z - mean) * inv); af0[7] = (short)f2bf((c.w - mean) * inv);
    float4 d = *(const float4*)&x[(size_t)(mbase + 16 + lo) * 32 + quad * 8];
    float4 e = *(const float4*)&x[(size_t)(mbase + 16 + lo) * 32 + quad * 8 + 4];
    af1[0] = (short)f2bf((d.x - mean) * inv); af1[1] = (short)f2bf((d.y - mean) * inv);
    af1[2] = (short)f2bf((d.z - mean) * inv); af1[3] = (short)f2bf((d.w - mean) * inv);
    af1[4] = (short)f2bf((e.x - mean) * inv); af1[5] = (short)f2bf((e.y - mean) * inv);
    af1[6] = (short)f2bf((e.z - mean) * inv); af1[7] = (short)f2bf((e.w - mean) * inv);
  }
  // Q (pre-scaled 1/16)
#pragma unroll 4
  for (int nt = 0; nt < 16; ++nt) {
    s16x8 bf = *(const s16x8*)&WqT[(size_t)(nt * 16 + lo) * 32 + quad * 8];
    f32x4 c0 = {0.f, 0.f, 0.f, 0.f}, c1 = {0.f, 0.f, 0.f, 0.f};
    c0 = __builtin_amdgcn_mfma_f32_16x16x32_bf16(af0, bf, c0, 0, 0, 0);
    c1 = __builtin_amdgcn_mfma_f32_16x16x32_bf16(af1, bf, c1, 0, 0, 0);
    const int col = nt * 16 + lo;
    const float bi = Wcb[col];
#pragma unroll
    for (int i = 0; i < 4; ++i) {
      Tw[(quad * 4 + i) * 264 + col]      = f2bf((c0[i] + bi) * 0.0625f);
      Tw[(16 + quad * 4 + i) * 264 + col] = f2bf((c1[i] + bi) * 0.0625f);
    }
  }
#pragma unroll
  for (int it = 0; it < 16; ++it) {
    const int gsub = it * 64 + lane;
    const int row = gsub >> 5, c16 = gsub & 31;
    *(u16x8*)&Qb[(size_t)(mbase + row) * 256 + c16 * 8] =
        *(const u16x8*)&Tw[row * 264 + c16 * 8];
  }
  // K
#pragma unroll 4
  for (int nt = 0; nt < 16; ++nt) {
    s16x8 bf = *(const s16x8*)&WqT[(size_t)(256 + nt * 16 + lo) * 32 + quad * 8];
    f32x4 c0 = {0.f, 0.f, 0.f, 0.f}, c1 = {0.f, 0.f, 0.f, 0.f};
    c0 = __builtin_amdgcn_mfma_f32_16x16x32_bf16(af0, bf, c0, 0, 0, 0);
    c1 = __builtin_amdgcn_mfma_f32_16x16x32_bf16(af1, bf, c1, 0, 0, 0);
    const int col = nt * 16 + lo;
    const float bi = Wcb[256 + col];
#pragma unroll
    for (int i = 0; i < 4; ++i) {
      Tw[(quad * 4 + i) * 264 + col]      = f2bf(c0[i] + bi);
      Tw[(16 + quad * 4 + i) * 264 + col] = f2bf(c1[i] + bi);
    }
  }
#pragma unroll
  for (int it = 0; it < 16; ++it) {
    const int gsub = it * 64 + lane;
    const int row = gsub >> 5, c16 = gsub & 31;
    *(u16x8*)&Kb[(size_t)(mbase + row) * 256 + c16 * 8] =
        *(const u16x8*)&Tw[row * 264 + c16 * 8];
  }
  // V transposed, kt-tiled: Vtt[(b*32+ktq)*8192 + d*32 + t_local]
#pragma unroll 4
  for (int nt2 = 0; nt2 < 16; ++nt2) {
    s16x8 aw = *(const s16x8*)&WqT[(size_t)(512 + nt2 * 16 + lo) * 32 + quad * 8];
    f32x4 c0 = {0.f, 0.f, 0.f, 0.f}, c1 = {0.f, 0.f, 0.f, 0.f};
    c0 = __builtin_amdgcn_mfma_f32_16x16x32_bf16(aw, af0, c0, 0, 0, 0);
    c1 = __builtin_amdgcn_mfma_f32_16x16x32_bf16(aw, af1, c1, 0, 0, 0);
#pragma unroll
    for (int i = 0; i < 4; ++i) {
      const int d = nt2 * 16 + quad * 4 + i;
      const float bv = Wcb[512 + d];
      Tw[d * 32 + lo]      = f2bf(c0[i] + bv);
      Tw[d * 32 + 16 + lo] = f2bf(c1[i] + bv);
    }
  }
  {
    const int ktq = (mbase >> 5) & 31;
    const size_t vb = ((size_t)b * 32 + ktq) * 8192;
#pragma unroll
    for (int it = 0; it < 16; ++it) {
      const int gsub = it * 64 + lane;
      *(u16x8*)&Vtt[vb + gsub * 8] = *(const u16x8*)&Tw[gsub * 8];
    }
  }
}

// ------ flash attention: depth-3 ring + rotating producer/consumer P-exchange ------
// 256 blocks x 512 thr (8 waves), 1 block/CU, ring 4x32KB, counted vmcnt (R5 ✓).
// Waves: th = w>>2 (tile), dq = w&3 (dim quarter). Per tile, a ROTATING producer
// wave (th*4 + ((s+1+2th)&3); the two tiles' producers 2 SIMDs apart) computes
// QK^T(s+1) from the drained slot s+1, softmax, bf16-pack, and writes the 32x32
// P-tile to LDS (double-buffered, stride-80B rows, quad (2g+hi) = A-fragment
// order, layout-equivalent to the R4/R5-verified shfl assembly). All 8 waves do
// PV(s) with 2 P-b128 + 4 V-b128 reads. Removes R5's 4x redundant K-reads/softmax
// (the 6k-cyc/step cost). lgkmcnt(0) before each barrier makes P cross-wave
// visible; prologue barrier covers all waves' slot-0 staging before P(0).
__global__ __launch_bounds__(512, 2) void attn_kernel(const unsigned short* __restrict__ Qb,
                                                      const unsigned short* __restrict__ Kb,
                                                      const unsigned short* __restrict__ Vtt,
                                                      const unsigned short* __restrict__ WfT,
                                                      const float* __restrict__ bfp,
                                                      const float* __restrict__ x,
                                                      const float* __restrict__ sgpart,
                                                      float* __restrict__ lsum,
                                                      unsigned int* __restrict__ total,
                                                      float* __restrict__ out) {
  __shared__ unsigned short SMEM[65536];      // 4 ring slots x 16384 shorts
  __shared__ unsigned short Pbuf[2][2][1280]; // [tile][slot][32 rows x 40 shorts]
  __shared__ float OlL[8][32];
  __shared__ float redf[8];
  const int g = blockIdx.x;
  const int b = (g & 7) * 4 + ((g >> 3) & 3);  // XCD (g%8) pinned: 4 batches per XCD
  const int p = g >> 5;                        // 0..7 -> groups p and 15-p
  const int tid = threadIdx.x;
  const int w = tid >> 6, lane = tid & 63;
  const int th = w >> 2, dq = w & 3;           // tile-in-group, dim quarter
  const int cl = lane & 31, hi = lane >> 5;

  const unsigned short* KbB = Kb + (size_t)b * 262144;
  const unsigned short* VtB = Vtt + (size_t)b * 262144;
  unsigned short* QbM = (unsigned short*)Qb;

  // staging addresses (R5-verified, 0 conflicts): source inverse-swizzled, dest linear
  const int c0 = tid, c1 = 512 + tid;
  const int ks0 = (c0 >> 5) * 256 + (((c0 & 31) ^ (c0 >> 5)) * 8);
  const int ks1 = (c1 >> 5) * 256 + (((c1 & 31) ^ (c1 >> 5)) * 8);
  const int vs0 = (c0 >> 2) * 32 + (((c0 & 3) ^ ((c0 >> 4) & 3)) * 8);
  const int vs1 = (c1 >> 2) * 32 + (((c1 & 3) ^ ((c1 >> 4) & 3)) * 8);
  const int kd0 = w * 512, kd1 = 4096 + w * 512;

  auto STAGE = [&](int t) {
    const unsigned short* kg = KbB + (size_t)t * 8192;
    const unsigned short* vg = VtB + (size_t)t * 8192;
    unsigned short* Lb = &SMEM[(t & 3) * 16384];
    g2l16(kg + ks0, Lb + kd0);
    g2l16(kg + ks1, Lb + kd1);
    g2l16(vg + vs0, Lb + 8192 + kd0);
    g2l16(vg + vs1, Lb + 8192 + kd1);
  };

  s16x8 qf[16];
  f32x16 O0, O1;
  float Ol = 0.f;
  const int vsz = (cl >> 2) & 3;
  const int cva = (hi ^ vsz) * 8, cvb = ((2 | hi) ^ vsz) * 8;

  // producer: QK^T(sp) -> softmax -> pack -> P[th][sp&1]
  auto PRODUCE = [&](int sp, int myti_) {
    const unsigned short* Lk = &SMEM[(sp & 3) * 16384];
    f32x16 Sx;
#pragma unroll
    for (int i = 0; i < 16; ++i) Sx[i] = 0.f;
#pragma unroll
    for (int cb = 0; cb < 16; ++cb) {
      const int ch = (2 * cb + hi) ^ cl;
      s16x8 kf = *(const s16x8*)&Lk[cl * 256 + ch * 8];
      Sx = __builtin_amdgcn_mfma_f32_32x32x16_bf16(kf, qf[cb], Sx, 0, 0, 0);
    }
    const bool diag = (sp == myti_);
    unsigned short* Pd = &Pbuf[th][sp & 1][0];
#pragma unroll
    for (int gq = 0; gq < 4; ++gq) {
      float ev[4];
#pragma unroll
      for (int q2 = 0; q2 < 4; ++q2) {
        const int r = gq * 4 + q2;
        const int trow = q2 + 8 * gq + 4 * hi;
        float e = __expf(Sx[r] - SM_M);
        if (diag && trow > cl) e = 0.f;
        ev[q2] = e;
        Ol += e;
      }
      u32x2 pr;
      pr[0] = (u32)f2bf(ev[0]) | ((u32)f2bf(ev[1]) << 16);
      pr[1] = (u32)f2bf(ev[2]) | ((u32)f2bf(ev[3]) << 16);
      *(u32x2*)&Pd[cl * 40 + (2 * gq + hi) * 4] = pr;
    }
  };

  auto run_phase = [&](int gph) {
    const int nk = 2 * gph + 2;
    const int myti = 2 * gph + th;
    const size_t qrow = ((size_t)b * 1024 + myti * 32 + cl) * 256;
#pragma unroll
    for (int cb = 0; cb < 16; ++cb)
      qf[cb] = *(const s16x8*)&Qb[qrow + cb * 16 + hi * 8];
#pragma unroll
    for (int i = 0; i < 16; ++i) { O0[i] = 0.f; O1[i] = 0.f; }
    Ol = 0.f;
    if (nk >= 3) {
      STAGE(0); STAGE(1); STAGE(2);
      asm volatile("s_waitcnt vmcnt(8)" ::: "memory");  // slot0 (+qf) landed
    } else {
      STAGE(0); STAGE(1);
      asm volatile("s_waitcnt vmcnt(4)" ::: "memory");
    }
    __builtin_amdgcn_s_barrier();                       // everyone's slot-0 visible
    if (w == th * 4 + ((2 * th) & 3)) PRODUCE(0, myti);
    for (int s = 0; s < nk; ++s) {
      asm volatile("s_waitcnt lgkmcnt(0)" ::: "memory");  // P-writes visible pre-barrier
      if (s + 2 < nk) asm volatile("s_waitcnt vmcnt(4)" ::: "memory");  // slot s+1 ready
      else            asm volatile("s_waitcnt vmcnt(0)" ::: "memory");
      __builtin_amdgcn_s_barrier();
      __builtin_amdgcn_sched_barrier(0);
      if (s + 3 < nk) STAGE(s + 3);
      if (s + 1 <= myti && w == th * 4 + ((s + 1 + 2 * th) & 3)) PRODUCE(s + 1, myti);
      if (s <= myti) {  // PV(s): P from LDS + V from ring slot s
        const unsigned short* Pp = &Pbuf[th][s & 1][0];
        s16x8 pa = *(const s16x8*)&Pp[cl * 40 + 8 * hi];
        s16x8 pb = *(const s16x8*)&Pp[cl * 40 + 16 + 8 * hi];
        const unsigned short* Lv = &SMEM[(s & 3) * 16384 + 8192];
        const int d0 = (dq * 64 + cl) * 32;
        s16x8 v0 = *(const s16x8*)&Lv[d0 + cva];
        s16x8 v1 = *(const s16x8*)&Lv[d0 + cvb];
        O0 = __builtin_amdgcn_mfma_f32_32x32x16_bf16(pa, v0, O0, 0, 0, 0);
        O0 = __builtin_amdgcn_mfma_f32_32x32x16_bf16(pb, v1, O0, 0, 0, 0);
        s16x8 v2 = *(const s16x8*)&Lv[d0 + 1024 + cva];
        s16x8 v3 = *(const s16x8*)&Lv[d0 + 1024 + cvb];
        O1 = __builtin_amdgcn_mfma_f32_32x32x16_bf16(pa, v2, O1, 0, 0, 0);
        O1 = __builtin_amdgcn_mfma_f32_32x32x16_bf16(pb, v3, O1, 0, 0, 0);
      }
    }
    Ol += __shfl_xor(Ol, 32);  // both hi-halves of this wave's produced steps
  };

  // ---- phase A: group p; park normalized O in this block's (dead) Qb rows ----
  run_phase(p);
  if (hi == 0) OlL[w][cl] = Ol;
  __syncthreads();
  {
    const float dsum = OlL[th * 4][cl] + OlL[th * 4 + 1][cl] +
                       OlL[th * 4 + 2][cl] + OlL[th * 4 + 3][cl];
    const size_t obase = ((size_t)b * 1024 + (2 * p + th) * 32) * 256;
#pragma unroll
    for (int r = 0; r < 16; ++r) {
      const int row = (r & 3) + 8 * (r >> 2) + 4 * hi;
      const float iv = 1.f / __shfl(dsum, row);
      QbM[obase + row * 256 + dq * 64 + cl]      = f2bf(O0[r] * iv);
      QbM[obase + row * 256 + dq * 64 + 32 + cl] = f2bf(O1[r] * iv);
    }
  }
  __syncthreads();  // OlL reuse + ring reuse guard before phase B

  // ---- phase B: group 15-p ----
  run_phase(15 - p);
  if (hi == 0) OlL[w][cl] = Ol;
  __syncthreads();
  unsigned short* OLs = SMEM;  // overlay: 64 x 264 bf16 (rows th*32+row)
  {
    const float dsum = OlL[th * 4][cl] + OlL[th * 4 + 1][cl] +
                       OlL[th * 4 + 2][cl] + OlL[th * 4 + 3][cl];
#pragma unroll
    for (int r = 0; r < 16; ++r) {
      const int row = (r & 3) + 8 * (r >> 2) + 4 * hi;
      const float iv = 1.f / __shfl(dsum, row);
      OLs[(th * 32 + row) * 264 + dq * 64 + cl]      = f2bf(O0[r] * iv);
      OLs[(th * 32 + row) * 264 + dq * 64 + 32 + cl] = f2bf(O1[r] * iv);
    }
  }
  __syncthreads();

  // ---- epilogue: 4 head GEMMs (waves 0..3, one 32-row tile each) + fused MSE ----
  float lacc = 0.f;
  if (w < 4) {
    const int tile = (w == 0) ? 2 * p : (w == 1) ? 2 * p + 1
                   : (w == 2) ? 30 - 2 * p : 31 - 2 * p;
    s16x8 af[16];
    if (w < 2) {
      const size_t abase = ((size_t)b * 1024 + tile * 32 + cl) * 256;
#pragma unroll
      for (int cb = 0; cb < 16; ++cb)
        af[cb] = *(const s16x8*)&QbM[abase + cb * 16 + hi * 8];
    } else {
      const int sub = w - 2;
#pragma unroll
      for (int cb = 0; cb < 16; ++cb)
        af[cb] = *(const s16x8*)&OLs[(sub * 32 + cl) * 264 + cb * 16 + hi * 8];
    }
    f32x16 hacc;
#pragma unroll
    for (int i = 0; i < 16; ++i) hacc[i] = 0.f;
#pragma unroll
    for (int cb = 0; cb < 16; ++cb) {
      s16x8 bfr = *(const s16x8*)&WfT[(size_t)cl * 256 + cb * 16 + hi * 8];
      hacc = __builtin_amdgcn_mfma_f32_32x32x16_bf16(af[cb], bfr, hacc, 0, 0, 0);
    }
    float S_ = 0.f, SS = 0.f;
#pragma unroll
    for (int i = 0; i < 8; ++i) {
      S_ += sgpart[(b * 8 + i) * 2];
      SS += sgpart[(b * 8 + i) * 2 + 1];
    }
    const float mean = S_ * (1.f / (float)L_SZ);
    const float var = (SS - S_ * mean) * (1.f / (float)(L_SZ - 1));
    const float invb = 1.f / (sqrtf(var) + 1e-5f);
    const float ba = bfp[cl];
#pragma unroll
    for (int r = 0; r < 16; ++r) {
      const int row = (r & 3) + 8 * (r >> 2) + 4 * hi;
      const int t = tile * 32 + row;
      if (t < 1023) {
        const float pr = hacc[r] + ba;
        const float tg = (x[(size_t)b * L_SZ + (t + 1) * 32 + cl] - mean) * invb;
        const float d = pr - tg;
        lacc += d * d;
      }
    }
#pragma unroll
    for (int off = 32; off >= 1; off >>= 1) lacc += __shfl_down(lacc, off);
  }
  if (lane == 0) redf[w] = lacc;
  __syncthreads();

  // ---- in-kernel loss finalize (device-scope counter pattern, verified R10) ----
  if (tid == 0) {
    atomicAdd(lsum, redf[0] + redf[1] + redf[2] + redf[3]);
    __threadfence();
    unsigned int prev = atomicAdd(total, 1u);
    if (prev == 255u) {
      float tot = atomicAdd(lsum, 0.0f);  // device-scope read including all adds
      out[0] = tot * (1.f / (float)(B_SZ * (T_SZ - 1) * PS_SZ));
    }
  }
}

extern "C" void kernel_launch(void* const* d_in, const int* in_sizes, int n_in,
                              void* d_out, int out_size, void* d_ws, size_t ws_size,
                              hipStream_t stream) {
  const float* x      = (const float*)d_in[0];
  const float* W_proj = (const float*)d_in[1];
  const float* b_proj = (const float*)d_in[2];
  const float* W_qkv  = (const float*)d_in[3];
  const float* b_qkv  = (const float*)d_in[4];
  const float* W_out  = (const float*)d_in[5];
  const float* b_out  = (const float*)d_in[6];
  const float* W_head = (const float*)d_in[7];
  const float* b_head = (const float*)d_in[8];
  float* out = (float*)d_out;
  char* ws = (char*)d_ws;

  unsigned short* Qb     = (unsigned short*)ws;
  unsigned short* Kb     = (unsigned short*)(ws + (16ull << 20));
  unsigned short* Vtt    = (unsigned short*)(ws + (32ull << 20));
  char* tail = ws + (48ull << 20);
  float*          Wcb    = (float*)tail;                        // 768 fp32 folded qkv bias
  unsigned short* WqT    = (unsigned short*)(tail + 4096);      // 768x32 bf16
  unsigned short* WfT    = (unsigned short*)(tail + 65536);     // 32x256 bf16
  float*          bfp    = (float*)(tail + 98304);              // 32 fp32
  float*          sgpart = (float*)(tail + 102400);             // 256x2 fp32
  unsigned int*   total  = (unsigned int*)(tail + 106496);      // 1 ctr
  float*          lsum   = (float*)(tail + 106496 + 64);        // 1 fp32

  prep_kernel<<<389, 256, 0, stream>>>(x, sgpart, W_proj, b_proj, W_qkv, b_qkv,
                                       W_out, b_out, W_head, b_head,
                                       Wcb, WqT, WfT, bfp, total, lsum);
  qkv_kernel<<<256, 256, 0, stream>>>(x, sgpart, WqT, Wcb, Qb, Kb, Vtt);
  attn_kernel<<<256, 512, 0, stream>>>(Qb, Kb, Vtt, WfT, bfp, x, sgpart, lsum, total, out);
}